// Round 4
// baseline (33.344 us; speedup 1.0000x reference)
//
#include <hip/hip_runtime.h>

#define BS 8
#define NN 1024
#define JJ 4
#define FF 32
#define NC 2

typedef float f4v __attribute__((ext_vector_type(4)));

// Fully fused: out[b,n,c] = sum_m sum_j WW[b,n,m,j] * y[b,m,j,c] + fc_b[c]
// where y[b,m,j,c] = sum_f x[b,m,f] * fc_w[c, j*FF+f].
//
// Grid = 256 blocks (1/CU), 1024 threads (16 waves). Each block owns 32
// consecutive output rows of one batch element b (32 blocks per b).
// Phase 1: each thread computes y[b][m=tid][*] into LDS (redundant across the
//          32 blocks sharing b — 0.85 us chip-equivalent, cheaper than a
//          separate kernel + launch dependency).
// Phase 2: stream WW (134 MB compulsory HBM) — 2 rows per wave, float4,
//          simple strided loop (best structure from R2).
__global__ void __launch_bounds__(1024) fused_gmul_fc_kernel(
    const float* __restrict__ WW, const float* __restrict__ x,
    const float* __restrict__ fc_w, const float* __restrict__ fc_b,
    float* __restrict__ out) {
    __shared__ float4 lyA[NN];  // (j0c0,j0c1,j1c0,j1c1) per m
    __shared__ float4 lyB[NN];  // (j2c0,j2c1,j3c0,j3c1) per m

    const int blk  = blockIdx.x;      // 0..255
    const int b    = blk >> 5;        // 32 blocks per batch element
    const int tid  = threadIdx.x;     // 0..1023
    const int wave = tid >> 6;
    const int lane = tid & 63;

    // ---- Phase 1: y[b][m=tid] -> LDS ----
    {
        const float4* xr =
            reinterpret_cast<const float4*>(x + ((size_t)b * NN + tid) * FF);
        float xv[FF];
#pragma unroll
        for (int q = 0; q < FF / 4; ++q) {
            float4 v = xr[q];
            xv[q * 4 + 0] = v.x; xv[q * 4 + 1] = v.y;
            xv[q * 4 + 2] = v.z; xv[q * 4 + 3] = v.w;
        }
        float a00 = 0.f, a01 = 0.f, a10 = 0.f, a11 = 0.f;
        float a20 = 0.f, a21 = 0.f, a30 = 0.f, a31 = 0.f;
        const float* w0 = fc_w;            // class 0 weights (uniform -> SGPR)
        const float* w1 = fc_w + JJ * FF;  // class 1 weights
#pragma unroll
        for (int f = 0; f < FF; ++f) {
            float xf = xv[f];
            a00 += xf * w0[0 * FF + f];  a01 += xf * w1[0 * FF + f];
            a10 += xf * w0[1 * FF + f];  a11 += xf * w1[1 * FF + f];
            a20 += xf * w0[2 * FF + f];  a21 += xf * w1[2 * FF + f];
            a30 += xf * w0[3 * FF + f];  a31 += xf * w1[3 * FF + f];
        }
        lyA[tid] = make_float4(a00, a01, a10, a11);
        lyB[tid] = make_float4(a20, a21, a30, a31);
    }
    __syncthreads();

    // ---- Phase 2: stream WW, 2 rows per wave ----
    const int row0 = blk * 32 + wave * 2;  // global row index b*NN + n
    const f4v* W0 = reinterpret_cast<const f4v*>(WW) + (size_t)row0 * NN;
    const f4v* W1 = W0 + NN;

    float s00 = 0.f, s01 = 0.f, s10 = 0.f, s11 = 0.f;
#pragma unroll 4
    for (int m = lane; m < NN; m += 64) {
        f4v w0 = W0[m];
        f4v w1 = W1[m];
        float4 ya = lyA[m];
        float4 yb = lyB[m];
        s00 += w0.x * ya.x + w0.y * ya.z + w0.z * yb.x + w0.w * yb.z;
        s01 += w0.x * ya.y + w0.y * ya.w + w0.z * yb.y + w0.w * yb.w;
        s10 += w1.x * ya.x + w1.y * ya.z + w1.z * yb.x + w1.w * yb.z;
        s11 += w1.x * ya.y + w1.y * ya.w + w1.z * yb.y + w1.w * yb.w;
    }
#pragma unroll
    for (int off = 32; off > 0; off >>= 1) {
        s00 += __shfl_down(s00, off, 64);
        s01 += __shfl_down(s01, off, 64);
        s10 += __shfl_down(s10, off, 64);
        s11 += __shfl_down(s11, off, 64);
    }
    if (lane == 0) {
        float b0 = fc_b[0], b1 = fc_b[1];
        out[(size_t)row0 * NC + 0] = s00 + b0;
        out[(size_t)row0 * NC + 1] = s01 + b1;
        out[(size_t)(row0 + 1) * NC + 0] = s10 + b0;
        out[(size_t)(row0 + 1) * NC + 1] = s11 + b1;
    }
}

extern "C" void kernel_launch(void* const* d_in, const int* in_sizes, int n_in,
                              void* d_out, int out_size, void* d_ws, size_t ws_size,
                              hipStream_t stream) {
    const float* WW   = (const float*)d_in[0];  // (BS, NN, NN, JJ) fp32
    const float* x    = (const float*)d_in[1];  // (BS, NN, FF) fp32
    const float* fc_w = (const float*)d_in[2];  // (NC, JJ*FF) fp32
    const float* fc_b = (const float*)d_in[3];  // (NC,) fp32
    float* out = (float*)d_out;                 // (BS, NN, NC) fp32

    int blocks = (BS * NN) / 32;  // 256 blocks, one per CU
    fused_gmul_fc_kernel<<<blocks, 1024, 0, stream>>>(WW, x, fc_w, fc_b, out);
}